// Round 6
// baseline (513.528 us; speedup 1.0000x reference)
//
#include <hip/hip_runtime.h>
#include <hip/hip_bf16.h>

#define NROWS 8192
#define K_SEL 4096
#define BINS 4096

// Fused: per-row MSE (one 256-thread block per row) + last-block top-k select.
__global__ __launch_bounds__(256) void fused_mse_topk(const float4* __restrict__ o4,
                                                      const float4* __restrict__ y4,
                                                      float* __restrict__ per,
                                                      unsigned* __restrict__ counter,
                                                      float* __restrict__ out) {
    const int tid = threadIdx.x;
    const int lane = tid & 63;
    const int wid = tid >> 6;

    // ---------------- phase 1: this block's row ----------------
    {
        const int row = blockIdx.x;
        const size_t base = (size_t)row * 2048;  // 8192 cols / 4

        float4 a[8], b[8];
        #pragma unroll
        for (int p = 0; p < 8; ++p) a[p] = o4[base + tid + p * 256];
        #pragma unroll
        for (int p = 0; p < 8; ++p) b[p] = y4[base + tid + p * 256];

        float acc = 0.0f;
        #pragma unroll
        for (int p = 0; p < 8; ++p) {
            float d0 = a[p].x - b[p].x;
            float d1 = a[p].y - b[p].y;
            float d2 = a[p].z - b[p].z;
            float d3 = a[p].w - b[p].w;
            acc = fmaf(d0, d0, acc);
            acc = fmaf(d1, d1, acc);
            acc = fmaf(d2, d2, acc);
            acc = fmaf(d3, d3, acc);
        }
        for (int off = 32; off > 0; off >>= 1) acc += __shfl_down(acc, off, 64);

        __shared__ float wsum[4];
        if (lane == 0) wsum[wid] = acc;
        __syncthreads();
        if (tid == 0) {
            per[row] = (wsum[0] + wsum[1] + wsum[2] + wsum[3]) * (1.0f / 8192.0f);
        }
    }

    // ---------------- last-block handoff ----------------
    __shared__ unsigned s_islast;
    if (tid == 0) {
        __threadfence();                       // release: per[row] visible device-wide
        unsigned old = atomicAdd(counter, 1u); // device-scope
        s_islast = (old == NROWS - 1) ? 1u : 0u;
    }
    __syncthreads();
    if (!s_islast) return;
    __threadfence();                           // acquire

    // ---------------- phase 2: top-k select (256 threads, 32 vals each) ----
    float v[32];
    #pragma unroll
    for (int p = 0; p < 32; ++p) v[p] = per[tid + p * 256];

    // global min/max
    float mn = v[0], mx = v[0];
    #pragma unroll
    for (int p = 1; p < 32; ++p) { mn = fminf(mn, v[p]); mx = fmaxf(mx, v[p]); }
    for (int off = 32; off > 0; off >>= 1) {
        mn = fminf(mn, __shfl_down(mn, off, 64));
        mx = fmaxf(mx, __shfl_down(mx, off, 64));
    }
    __shared__ float wmn[4], wmx[4];
    __shared__ float s_lo, s_hi, s_T;
    __shared__ int s_bin, s_kkb;
    __shared__ unsigned hist[BINS];
    __shared__ float cand[256];
    __shared__ unsigned ccnt;
    __shared__ unsigned wtot[4];
    __shared__ float wss[4], wcg[4];

    if (lane == 0) { wmn[wid] = mn; wmx[wid] = mx; }
    __syncthreads();
    if (tid == 0) {
        float a2 = wmn[0], b2 = wmx[0];
        for (int i = 1; i < 4; ++i) { a2 = fminf(a2, wmn[i]); b2 = fmaxf(b2, wmx[i]); }
        s_lo = a2; s_hi = b2;
    }
    __syncthreads();
    const float lo = s_lo, hi = s_hi;

    float T;
    if (hi <= lo) {
        T = lo;
    } else {
        const float scale = (float)BINS / (hi - lo);
        const float w = (hi - lo) * (1.0f / (float)BINS);

        #pragma unroll
        for (int i = 0; i < BINS / 256; ++i) hist[tid + i * 256] = 0;
        __syncthreads();
        #pragma unroll
        for (int p = 0; p < 32; ++p) {
            int idx = (int)((v[p] - lo) * scale);
            idx = idx < 0 ? 0 : (idx > BINS - 1 ? BINS - 1 : idx);
            atomicAdd(&hist[idx], 1u);
        }
        __syncthreads();

        // suffix scan over 256 groups of 16 bins, descending: thread tid owns g=255-tid
        const int g = 255 - tid;
        unsigned c = 0;
        #pragma unroll
        for (int j = 0; j < 16; ++j) c += hist[16 * g + j];
        unsigned x = c;
        for (int off = 1; off < 64; off <<= 1) {
            unsigned t2 = __shfl_up(x, off, 64);
            if (lane >= off) x += t2;
        }
        if (lane == 63) wtot[wid] = x;
        __syncthreads();
        unsigned basec = 0;
        for (int i = 0; i < wid; ++i) basec += wtot[i];
        const unsigned incl = basec + x;   // count of values in bins >= 16g

        if (incl >= K_SEL && (incl - c) < K_SEL) {
            unsigned cum = incl - c;
            for (int bb = 16 * g + 15; bb >= 16 * g; --bb) {
                unsigned hb = hist[bb];
                if (cum + hb >= K_SEL) {
                    s_bin = bb;
                    s_kkb = (int)(K_SEL - cum);
                    break;
                }
                cum += hb;
            }
        }
        __syncthreads();
        const int bin = s_bin;
        const int kkb = s_kkb;

        if (tid == 0) ccnt = 0;
        __syncthreads();
        #pragma unroll
        for (int p = 0; p < 32; ++p) {
            int idx = (int)((v[p] - lo) * scale);
            idx = idx < 0 ? 0 : (idx > BINS - 1 ? BINS - 1 : idx);
            if (idx == bin) {
                unsigned aa = atomicAdd(&ccnt, 1u);
                if (aa < 256) cand[aa] = v[p];
            }
        }
        __syncthreads();

        if (tid == 0) {
            int n = (int)(ccnt < 256u ? ccnt : 256u);
            float thr;
            if (n > 0 && n <= 64 && kkb <= n) {
                thr = cand[0];
                for (int e = 0; e < kkb; ++e) {
                    float best = -1e30f; int bi = 0;
                    for (int i = 0; i < n; ++i) {
                        float cc = cand[i];
                        if (cc > best) { best = cc; bi = i; }
                    }
                    cand[bi] = -1e30f;
                    thr = best;
                }
            } else {
                thr = lo + (float)(bin + 1) * w;  // self-correcting formula absorbs this
            }
            s_T = thr;
        }
        __syncthreads();
        T = s_T;
    }

    // S = sum(v > T) + (k - cnt(v > T)) * T
    float ssum = 0.0f, cgt = 0.0f;
    #pragma unroll
    for (int p = 0; p < 32; ++p) {
        if (v[p] > T) { ssum += v[p]; cgt += 1.0f; }
    }
    for (int off = 32; off > 0; off >>= 1) {
        ssum += __shfl_down(ssum, off, 64);
        cgt += __shfl_down(cgt, off, 64);
    }
    if (lane == 0) { wss[wid] = ssum; wcg[wid] = cgt; }
    __syncthreads();
    if (tid == 0) {
        float ts = 0.0f, tc = 0.0f;
        for (int i = 0; i < 4; ++i) { ts += wss[i]; tc += wcg[i]; }
        out[0] = ts + ((float)K_SEL - tc) * T;
    }
}

extern "C" void kernel_launch(void* const* d_in, const int* in_sizes, int n_in,
                              void* d_out, int out_size, void* d_ws, size_t ws_size,
                              hipStream_t stream) {
    const float* o = (const float*)d_in[0];
    const float* y = (const float*)d_in[1];
    float* per = (float*)d_ws;                                   // 8192 floats
    unsigned* counter = (unsigned*)((char*)d_ws + 32768);        // 1 uint
    float* out = (float*)d_out;

    (void)hipMemsetAsync(counter, 0, sizeof(unsigned), stream);
    fused_mse_topk<<<NROWS, 256, 0, stream>>>((const float4*)o, (const float4*)y,
                                              per, counter, out);
}

// Round 7
// 100.542 us; speedup vs baseline: 5.1076x; 5.1076x over previous
//
#include <hip/hip_runtime.h>
#include <hip/hip_bf16.h>

#define K_SEL 4096
#define BINS 4096

// Phase 1: per-row mean of squared diffs. One 256-thread block per row.
// All 16 float4 loads issued before any use; sched_barrier(0) pins them
// so the scheduler cannot sink loads back into load-use pairs.
__global__ __launch_bounds__(256) void row_mse_kernel(const float4* __restrict__ o4,
                                                      const float4* __restrict__ y4,
                                                      float* __restrict__ per) {
    const int row = blockIdx.x;
    const int tid = threadIdx.x;
    const size_t base = (size_t)row * 2048;  // 8192 cols / 4

    float4 a[8], b[8];
    #pragma unroll
    for (int p = 0; p < 8; ++p) {
        a[p] = o4[base + tid + p * 256];
        b[p] = y4[base + tid + p * 256];
    }
    __builtin_amdgcn_sched_barrier(0);  // keep all 16 loads issued above

    float acc = 0.0f;
    #pragma unroll
    for (int p = 0; p < 8; ++p) {
        float d0 = a[p].x - b[p].x;
        float d1 = a[p].y - b[p].y;
        float d2 = a[p].z - b[p].z;
        float d3 = a[p].w - b[p].w;
        acc = fmaf(d0, d0, acc);
        acc = fmaf(d1, d1, acc);
        acc = fmaf(d2, d2, acc);
        acc = fmaf(d3, d3, acc);
    }

    for (int off = 32; off > 0; off >>= 1) acc += __shfl_down(acc, off, 64);

    __shared__ float wsum[4];
    const int lane = tid & 63;
    const int wid = tid >> 6;
    if (lane == 0) wsum[wid] = acc;
    __syncthreads();
    if (tid == 0) {
        per[row] = (wsum[0] + wsum[1] + wsum[2] + wsum[3]) * (1.0f / 8192.0f);
    }
}

// Phase 2: single 1024-thread block. Linear-bin select of the k-th largest
// (k=4096), then S = sum(v > T) + (k - cnt(v > T)) * T  (self-correcting).
__global__ __launch_bounds__(1024) void topk_sum_kernel(const float* __restrict__ per,
                                                        float* __restrict__ out) {
    const int tid = threadIdx.x;
    const int lane = tid & 63;
    const int wid = tid >> 6;

    float v[8];
    #pragma unroll
    for (int p = 0; p < 8; ++p) v[p] = per[tid + p * 1024];

    // ---- global min/max ----
    float mn = v[0], mx = v[0];
    #pragma unroll
    for (int p = 1; p < 8; ++p) { mn = fminf(mn, v[p]); mx = fmaxf(mx, v[p]); }
    for (int off = 32; off > 0; off >>= 1) {
        mn = fminf(mn, __shfl_down(mn, off, 64));
        mx = fmaxf(mx, __shfl_down(mx, off, 64));
    }
    __shared__ float wmn[16], wmx[16];
    __shared__ float s_lo, s_hi, s_T;
    __shared__ int s_bin, s_kkb;
    if (lane == 0) { wmn[wid] = mn; wmx[wid] = mx; }
    __syncthreads();
    if (tid == 0) {
        float a = wmn[0], b = wmx[0];
        for (int i = 1; i < 16; ++i) { a = fminf(a, wmn[i]); b = fmaxf(b, wmx[i]); }
        s_lo = a; s_hi = b;
    }
    __syncthreads();
    const float lo = s_lo, hi = s_hi;

    float T;
    __shared__ unsigned hist[BINS];
    __shared__ float cand[1024];
    __shared__ unsigned ccnt;

    if (hi <= lo) {
        T = lo;  // all values equal
    } else {
        const float scale = (float)BINS / (hi - lo);
        const float w = (hi - lo) * (1.0f / (float)BINS);

        #pragma unroll
        for (int i = 0; i < BINS / 1024; ++i) hist[tid + i * 1024] = 0;
        __syncthreads();
        #pragma unroll
        for (int p = 0; p < 8; ++p) {
            int idx = (int)((v[p] - lo) * scale);
            idx = idx < 0 ? 0 : (idx > BINS - 1 ? BINS - 1 : idx);
            atomicAdd(&hist[idx], 1u);
        }
        __syncthreads();

        // suffix scan (descending bins): thread tid owns group g = 1023-tid (4 bins)
        const int g = 1023 - tid;
        unsigned c = hist[4 * g] + hist[4 * g + 1] + hist[4 * g + 2] + hist[4 * g + 3];
        unsigned x = c;
        for (int off = 1; off < 64; off <<= 1) {
            unsigned t2 = __shfl_up(x, off, 64);
            if (lane >= off) x += t2;
        }
        __shared__ unsigned wtot[16];
        if (lane == 63) wtot[wid] = x;
        __syncthreads();
        unsigned basec = 0;
        for (int i = 0; i < wid; ++i) basec += wtot[i];
        const unsigned incl = basec + x;  // count of values in bins >= 4g

        if (incl >= K_SEL && (incl - c) < K_SEL) {
            unsigned cum = incl - c;
            for (int b = 4 * g + 3; b >= 4 * g; --b) {
                unsigned hb = hist[b];
                if (cum + hb >= K_SEL) {
                    s_bin = b;
                    s_kkb = (int)(K_SEL - cum);
                    break;
                }
                cum += hb;
            }
        }
        __syncthreads();
        const int bin = s_bin;
        const int kkb = s_kkb;

        if (tid == 0) ccnt = 0;
        __syncthreads();
        #pragma unroll
        for (int p = 0; p < 8; ++p) {
            int idx = (int)((v[p] - lo) * scale);
            idx = idx < 0 ? 0 : (idx > BINS - 1 ? BINS - 1 : idx);
            if (idx == bin) {
                unsigned a = atomicAdd(&ccnt, 1u);
                if (a < 1024) cand[a] = v[p];
            }
        }
        __syncthreads();

        if (tid == 0) {
            int n = (int)(ccnt < 1024u ? ccnt : 1024u);
            float thr;
            if (n > 0 && n <= 64 && kkb <= n) {
                thr = cand[0];
                for (int e = 0; e < kkb; ++e) {
                    float best = -1e30f; int bi = 0;
                    for (int i = 0; i < n; ++i) {
                        float cc = cand[i];
                        if (cc > best) { best = cc; bi = i; }
                    }
                    cand[bi] = -1e30f;
                    thr = best;
                }
            } else {
                thr = lo + (float)(bin + 1) * w;  // absorbed by final formula
            }
            s_T = thr;
        }
        __syncthreads();
        T = s_T;
    }

    // ---- final: S = sum(v > T) + (k - cnt(v > T)) * T ----
    float ssum = 0.0f, cgt = 0.0f;
    #pragma unroll
    for (int p = 0; p < 8; ++p) {
        if (v[p] > T) { ssum += v[p]; cgt += 1.0f; }
    }
    for (int off = 32; off > 0; off >>= 1) {
        ssum += __shfl_down(ssum, off, 64);
        cgt += __shfl_down(cgt, off, 64);
    }
    __shared__ float wss[16], wcg[16];
    if (lane == 0) { wss[wid] = ssum; wcg[wid] = cgt; }
    __syncthreads();
    if (tid == 0) {
        float ts = 0.0f, tc = 0.0f;
        for (int i = 0; i < 16; ++i) { ts += wss[i]; tc += wcg[i]; }
        out[0] = ts + ((float)K_SEL - tc) * T;
    }
}

extern "C" void kernel_launch(void* const* d_in, const int* in_sizes, int n_in,
                              void* d_out, int out_size, void* d_ws, size_t ws_size,
                              hipStream_t stream) {
    const float* o = (const float*)d_in[0];
    const float* y = (const float*)d_in[1];
    float* per = (float*)d_ws;       // 8192 floats = 32 KB scratch
    float* out = (float*)d_out;      // 1 float

    row_mse_kernel<<<8192, 256, 0, stream>>>((const float4*)o, (const float4*)y, per);
    topk_sum_kernel<<<1, 1024, 0, stream>>>(per, out);
}